// Round 1
// baseline (891.811 us; speedup 1.0000x reference)
//
#include <hip/hip_runtime.h>
#include <math.h>

typedef unsigned short u16;
typedef __attribute__((ext_vector_type(8))) short short8;
typedef __attribute__((ext_vector_type(4))) float f32x4;
typedef __attribute__((ext_vector_type(4))) unsigned short u16x4;

#define HN 16
#define KVH 8
#define DH 256
#define HID 3584
#define T_LEN 3072
#define QKV_N 8192   // H*D + 2*KV*D
#define O_N 4096     // H*D
#define WIN 1535
#define SCALING 0.0625f
#define SOFTCAP 50.0f

__device__ __forceinline__ u16 f2bf(float f) {
  unsigned u = __float_as_uint(f);
  u += 0x7FFFu + ((u >> 16) & 1u);
  return (u16)(u >> 16);
}
__device__ __forceinline__ float bf2f(u16 b) {
  return __uint_as_float(((unsigned)b) << 16);
}

__device__ __forceinline__ void gload_lds16(const void* g, void* l) {
  __builtin_amdgcn_global_load_lds(
      (const __attribute__((address_space(1))) void*)g,
      (__attribute__((address_space(3))) void*)l, 16, 0, 0);
}

__device__ __forceinline__ f32x4 mfma_bf16(short8 a, short8 b, f32x4 c) {
  return __builtin_amdgcn_mfma_f32_16x16x32_bf16(a, b, c, 0, 0, 0);
}

// ---------------- f32 -> bf16 convert (n % 4 == 0) ----------------
__global__ __launch_bounds__(256) void cvt_kernel(const float* __restrict__ in,
                                                  u16* __restrict__ out, int n) {
  int i = (blockIdx.x * 256 + threadIdx.x) * 4;
  if (i >= n) return;
  float4 v = *(const float4*)(in + i);
  u16x4 o;
  o[0] = f2bf(v.x); o[1] = f2bf(v.y); o[2] = f2bf(v.z); o[3] = f2bf(v.w);
  *(u16x4*)(out + i) = o;
}

// ---------------- GEMM: C[M,N] = A[M,K] * B[N,K]^T  (m97 structure) ---------
// 128x128 tile, BK=32, 256 thr = 4 waves (2x2), wave = 64x64 = 4x4 frags.
template <int OUT_BF16>
__global__ __launch_bounds__(256) void gemm_bt(const u16* __restrict__ A,
                                               const u16* __restrict__ B,
                                               void* __restrict__ Cv,
                                               int M, int N, int K, int ntn) {
  __shared__ u16 sA[128 * 32];
  __shared__ u16 sB[128 * 32];
  const int bm = blockIdx.x / ntn, bn = blockIdx.x % ntn;
  const int row0 = bm * 128, col0 = bn * 128;
  const int tid = threadIdx.x, lane = tid & 63, w = tid >> 6;
  const int wr = w >> 1, wc = w & 1;
  f32x4 acc[4][4] = {};

  // staging: wave w covers rows [w*32, w*32+32): 2 instrs x 16 rows.
  const u16* Abase = A + (size_t)(row0 + w * 32 + (lane >> 2)) * K + (lane & 3) * 8;
  const u16* Bbase = B + (size_t)(col0 + w * 32 + (lane >> 2)) * K + (lane & 3) * 8;
  u16* sAdst = &sA[w * 32 * 32];
  u16* sBdst = &sB[w * 32 * 32];

  for (int k0 = 0; k0 < K; k0 += 32) {
    gload_lds16(Abase + k0, sAdst);
    gload_lds16(Abase + k0 + (size_t)16 * K, sAdst + 16 * 32);
    gload_lds16(Bbase + k0, sBdst);
    gload_lds16(Bbase + k0 + (size_t)16 * K, sBdst + 16 * 32);
    __syncthreads();

    short8 af[4], bfr[4];
#pragma unroll
    for (int mi = 0; mi < 4; ++mi)
      af[mi] = *(const short8*)&sA[(wr * 64 + mi * 16 + (lane & 15)) * 32 + (lane >> 4) * 8];
#pragma unroll
    for (int ni = 0; ni < 4; ++ni)
      bfr[ni] = *(const short8*)&sB[(wc * 64 + ni * 16 + (lane & 15)) * 32 + (lane >> 4) * 8];
#pragma unroll
    for (int mi = 0; mi < 4; ++mi)
#pragma unroll
      for (int ni = 0; ni < 4; ++ni)
        acc[mi][ni] = mfma_bf16(af[mi], bfr[ni], acc[mi][ni]);
    __syncthreads();
  }

#pragma unroll
  for (int mi = 0; mi < 4; ++mi) {
#pragma unroll
    for (int ni = 0; ni < 4; ++ni) {
      const int r = row0 + wr * 64 + mi * 16 + (lane >> 4) * 4;
      const int c = col0 + wc * 64 + ni * 16 + (lane & 15);
#pragma unroll
      for (int j = 0; j < 4; ++j) {
        float v = acc[mi][ni][j];
        if (OUT_BF16)
          ((u16*)Cv)[(size_t)(r + j) * N + c] = f2bf(v);
        else
          ((float*)Cv)[(size_t)(r + j) * N + c] = v;
      }
    }
  }
}

// ---------------- RoPE (NeoX) in-place on q,k of qkv (bf16) ----------------
__global__ __launch_bounds__(256) void rope_kernel(u16* __restrict__ qkv) {
  int idx = blockIdx.x * 256 + threadIdx.x;  // T * 24 * 128
  int d = idx & 127;
  int hh = (idx >> 7) % 24;
  int t = idx / (24 * 128);
  if (t >= T_LEN) return;
  size_t base = (size_t)t * QKV_N + (hh < HN ? hh * DH : HN * DH + (hh - HN) * DH);
  float inv = exp2f((float)d * (-13.287712379549449f / 128.0f));  // 10000^(-d/128)
  float ang = (float)t * inv;
  float s, c;
  __sincosf(ang, &s, &c);  // placeholder; replaced below by accurate version
  s = sinf(ang); c = cosf(ang);
  float x1 = bf2f(qkv[base + d]);
  float x2 = bf2f(qkv[base + d + 128]);
  qkv[base + d] = f2bf(x1 * c - x2 * s);
  qkv[base + d + 128] = f2bf(x2 * c + x1 * s);
}

// ---------------- flash attention, softcap + sliding window ----------------
// grid (T/64, H); 256 thr = 4 waves, wave w owns q rows qb+w*16..+15.
__global__ __launch_bounds__(256) void attn_kernel(const u16* __restrict__ qkv,
                                                   u16* __restrict__ aout) {
  const int qb = blockIdx.x * 64;
  const int h = blockIdx.y;
  const int kvh = h >> 1;
  const int tid = threadIdx.x, lane = tid & 63, w = tid >> 6;

  __shared__ u16 sK[32 * 256];      // linear store, XOR-swizzled source
  __shared__ u16 sVt[256 * 40];     // V^T, padded stride 40
  __shared__ u16 sP[4][16 * 40];    // per-wave P, padded stride 40

  // Q fragments in registers (row = lane&15, k = (lane>>4)*8 + j within chunk)
  const int qrow = qb + w * 16 + (lane & 15);
  short8 qf[8];
  {
    const u16* qp = qkv + (size_t)qrow * QKV_N + h * DH + (lane >> 4) * 8;
#pragma unroll
    for (int kc = 0; kc < 8; ++kc) qf[kc] = *(const short8*)(qp + kc * 32);
  }

  f32x4 O[16];
#pragma unroll
  for (int i = 0; i < 16; ++i) O[i] = f32x4{0.f, 0.f, 0.f, 0.f};
  float mrow[4] = {-1e30f, -1e30f, -1e30f, -1e30f};
  float lrow[4] = {0.f, 0.f, 0.f, 0.f};

  int jmin = qb - WIN; if (jmin < 0) jmin = 0;
  const int jt0 = jmin >> 5, jt1 = (qb + 63) >> 5;

  for (int jt = jt0; jt <= jt1; ++jt) {
    const int jb = jt * 32;
    // ---- stage K tile [32][256] via global_load_lds, source pre-swizzled:
    // LDS[r][c16] holds global chunk (c16 ^ (r&7)) of row jb+r.
#pragma unroll
    for (int i = 0; i < 4; ++i) {
      int rloc = (w * 4 + i) * 2 + (lane >> 5);
      int sc = (lane & 31) ^ (rloc & 7);
      const u16* g = qkv + (size_t)(jb + rloc) * QKV_N + HN * DH + kvh * DH + sc * 8;
      gload_lds16(g, &sK[(w * 4 + i) * 2 * 256]);
    }
    // ---- stage V^T: thread tid owns column d = tid; gather 32 keys.
    {
      const u16* vg = qkv + (size_t)jb * QKV_N + HN * DH + KVH * DH + kvh * DH + tid;
#pragma unroll
      for (int kb = 0; kb < 32; kb += 8) {
        short8 tv;
#pragma unroll
        for (int j = 0; j < 8; ++j) tv[j] = (short)vg[(size_t)(kb + j) * QKV_N];
        *(short8*)&sVt[tid * 40 + kb] = tv;
      }
    }
    __syncthreads();

    // ---- S = Q K^T (16x32 per wave, 2 col-frags)
    f32x4 S[2] = {f32x4{0.f, 0.f, 0.f, 0.f}, f32x4{0.f, 0.f, 0.f, 0.f}};
#pragma unroll
    for (int nf = 0; nf < 2; ++nf) {
      int krow = nf * 16 + (lane & 15);
#pragma unroll
      for (int kc = 0; kc < 8; ++kc) {
        int chunk = (kc * 4 + (lane >> 4)) ^ (krow & 7);
        short8 kf = *(const short8*)&sK[krow * 256 + chunk * 8];
        S[nf] = mfma_bf16(qf[kc], kf, S[nf]);
      }
    }

    // ---- softcap + mask + online softmax (row = (lane>>4)*4 + r)
#pragma unroll
    for (int r = 0; r < 4; ++r) {
      const int irow = qb + w * 16 + (lane >> 4) * 4 + r;
      float sv[2];
      float mx = -1e30f;
#pragma unroll
      for (int nf = 0; nf < 2; ++nf) {
        int j = jb + nf * 16 + (lane & 15);
        float x = S[nf][r] * (SCALING / SOFTCAP);
        float ax = fabsf(x);
        float e = __expf(-2.0f * ax);
        float th = (1.0f - e) / (1.0f + e);
        th = x >= 0.0f ? th : -th;
        float sval = SOFTCAP * th;
        bool ok = (j <= irow) && (irow - j <= WIN);
        sv[nf] = ok ? sval : -1e30f;
        mx = fmaxf(mx, sv[nf]);
      }
#pragma unroll
      for (int off = 8; off >= 1; off >>= 1) mx = fmaxf(mx, __shfl_xor(mx, off));
      float mnew = fmaxf(mrow[r], mx);
      float alpha = __expf(mrow[r] - mnew);
      float rs = 0.f;
      u16 pb[2];
#pragma unroll
      for (int nf = 0; nf < 2; ++nf) {
        float e = (sv[nf] > -5e29f) ? __expf(sv[nf] - mnew) : 0.0f;
        rs += e;
        pb[nf] = f2bf(e);
      }
#pragma unroll
      for (int off = 8; off >= 1; off >>= 1) rs += __shfl_xor(rs, off);
      lrow[r] = lrow[r] * alpha + rs;
      mrow[r] = mnew;
#pragma unroll
      for (int nf2 = 0; nf2 < 16; ++nf2) O[nf2][r] *= alpha;
      int ql = (lane >> 4) * 4 + r;
      sP[w][ql * 40 + (lane & 15)] = pb[0];
      sP[w][ql * 40 + 16 + (lane & 15)] = pb[1];
    }

    // ---- O += P V   (P: A-frag from sP; V: B-frag from sVt)
    short8 pf = *(const short8*)&sP[w][(lane & 15) * 40 + (lane >> 4) * 8];
#pragma unroll
    for (int nf = 0; nf < 16; ++nf) {
      int d = nf * 16 + (lane & 15);
      short8 vf = *(const short8*)&sVt[d * 40 + (lane >> 4) * 8];
      O[nf] = mfma_bf16(pf, vf, O[nf]);
    }
    __syncthreads();
  }

  // ---- normalize + store bf16
#pragma unroll
  for (int nf = 0; nf < 16; ++nf) {
    int d = nf * 16 + (lane & 15);
#pragma unroll
    for (int r = 0; r < 4; ++r) {
      int trow = qb + w * 16 + (lane >> 4) * 4 + r;
      aout[(size_t)trow * O_N + h * DH + d] = f2bf(O[nf][r] / lrow[r]);
    }
  }
}

// ---------------- host launcher ----------------
extern "C" void kernel_launch(void* const* d_in, const int* in_sizes, int n_in,
                              void* d_out, int out_size, void* d_ws, size_t ws_size,
                              hipStream_t stream) {
  const float* hidden = (const float*)d_in[1];
  const float* w_qkv = (const float*)d_in[2];
  const float* w_o = (const float*)d_in[3];
  float* out = (float*)d_out;
  char* ws = (char*)d_ws;

  const size_t HB_OFF = 0;                          // 3072*3584*2 = 22,020,096
  const size_t WQKV_OFF = 22020096;                 // 8192*3584*2 = 58,720,256
  const size_t QKV_OFF = WQKV_OFF + 58720256;       // 3072*8192*2 = 50,331,648
  const size_t ATTN_OFF = WQKV_OFF;                 // alias (after GEMM1): 25,165,824
  const size_t WO_OFF = WQKV_OFF + 25165824;        // alias: 3584*4096*2 = 29,360,128
  // total ws needed: 131,072,000 bytes

  u16* hb = (u16*)(ws + HB_OFF);
  u16* wqkvb = (u16*)(ws + WQKV_OFF);
  u16* qkvb = (u16*)(ws + QKV_OFF);
  u16* attnb = (u16*)(ws + ATTN_OFF);
  u16* wob = (u16*)(ws + WO_OFF);

  {
    int n = T_LEN * HID;  // 11,010,048
    cvt_kernel<<<dim3((n / 4 + 255) / 256), 256, 0, stream>>>(hidden, hb, n);
  }
  {
    int n = QKV_N * HID;  // 29,360,128
    cvt_kernel<<<dim3((n / 4 + 255) / 256), 256, 0, stream>>>(w_qkv, wqkvb, n);
  }
  gemm_bt<1><<<dim3(24 * 64), 256, 0, stream>>>(hb, wqkvb, qkvb, T_LEN, QKV_N, HID, 64);
  {
    int n = T_LEN * 24 * 128;  // 9,437,184
    rope_kernel<<<dim3(n / 256), 256, 0, stream>>>(qkvb);
  }
  {
    int n = HID * O_N;  // 14,680,064
    cvt_kernel<<<dim3((n / 4 + 255) / 256), 256, 0, stream>>>(w_o, wob, n);
  }
  attn_kernel<<<dim3(T_LEN / 64, HN), 256, 0, stream>>>(qkvb, attnb);
  gemm_bt<0><<<dim3(24 * 28), 256, 0, stream>>>(attnb, wob, out, T_LEN, HID, O_N, 28);
}

// Round 3
// 754.839 us; speedup vs baseline: 1.1815x; 1.1815x over previous
//
#include <hip/hip_runtime.h>
#include <math.h>

typedef unsigned short u16;
typedef __attribute__((ext_vector_type(8))) short short8;
typedef __attribute__((ext_vector_type(4))) float f32x4;
typedef __attribute__((ext_vector_type(4))) unsigned short u16x4;

#define HN 16
#define KVH 8
#define DH 256
#define HID 3584
#define T_LEN 3072
#define QKV_N 8192   // H*D + 2*KV*D
#define O_N 4096     // H*D
#define WIN 1535
#define SCALING 0.0625f
#define SOFTCAP 50.0f
#define KOFF 4096    // HN*DH
#define VOFF 6144    // HN*DH + KVH*DH
#define PSTR 72
#define NJT 48       // T_LEN/64

__device__ __forceinline__ u16 f2bf(float f) {
  unsigned u = __float_as_uint(f);
  u += 0x7FFFu + ((u >> 16) & 1u);
  return (u16)(u >> 16);
}
__device__ __forceinline__ float bf2f(u16 b) {
  return __uint_as_float(((unsigned)b) << 16);
}

__device__ __forceinline__ void gload_lds16(const void* g, void* l) {
  __builtin_amdgcn_global_load_lds(
      (const __attribute__((address_space(1))) void*)g,
      (__attribute__((address_space(3))) void*)l, 16, 0, 0);
}

__device__ __forceinline__ f32x4 mfma_bf16(short8 a, short8 b, f32x4 c) {
  return __builtin_amdgcn_mfma_f32_16x16x32_bf16(a, b, c, 0, 0, 0);
}

// ---------------- f32 -> bf16 convert (n % 4 == 0) ----------------
__global__ __launch_bounds__(256) void cvt_kernel(const float* __restrict__ in,
                                                  u16* __restrict__ out, int n) {
  int i = (blockIdx.x * 256 + threadIdx.x) * 4;
  if (i >= n) return;
  float4 v = *(const float4*)(in + i);
  u16x4 o;
  o[0] = f2bf(v.x); o[1] = f2bf(v.y); o[2] = f2bf(v.z); o[3] = f2bf(v.w);
  *(u16x4*)(out + i) = o;
}

// ---------------- GEMM: C[M,N] = A[M,K] * B[N,K]^T  (m97 structure) ---------
template <int OUT_BF16>
__global__ __launch_bounds__(256) void gemm_bt(const u16* __restrict__ A,
                                               const u16* __restrict__ B,
                                               void* __restrict__ Cv,
                                               int M, int N, int K, int ntn) {
  __shared__ u16 sA[128 * 32];
  __shared__ u16 sB[128 * 32];
  const int bm = blockIdx.x / ntn, bn = blockIdx.x % ntn;
  const int row0 = bm * 128, col0 = bn * 128;
  const int tid = threadIdx.x, lane = tid & 63, w = tid >> 6;
  const int wr = w >> 1, wc = w & 1;
  f32x4 acc[4][4] = {};
  (void)M;

  const u16* Abase = A + (size_t)(row0 + w * 32 + (lane >> 2)) * K + (lane & 3) * 8;
  const u16* Bbase = B + (size_t)(col0 + w * 32 + (lane >> 2)) * K + (lane & 3) * 8;
  u16* sAdst = &sA[w * 32 * 32];
  u16* sBdst = &sB[w * 32 * 32];

  for (int k0 = 0; k0 < K; k0 += 32) {
    gload_lds16(Abase + k0, sAdst);
    gload_lds16(Abase + k0 + (size_t)16 * K, sAdst + 16 * 32);
    gload_lds16(Bbase + k0, sBdst);
    gload_lds16(Bbase + k0 + (size_t)16 * K, sBdst + 16 * 32);
    __syncthreads();

    short8 af[4], bfr[4];
#pragma unroll
    for (int mi = 0; mi < 4; ++mi)
      af[mi] = *(const short8*)&sA[(wr * 64 + mi * 16 + (lane & 15)) * 32 + (lane >> 4) * 8];
#pragma unroll
    for (int ni = 0; ni < 4; ++ni)
      bfr[ni] = *(const short8*)&sB[(wc * 64 + ni * 16 + (lane & 15)) * 32 + (lane >> 4) * 8];
#pragma unroll
    for (int mi = 0; mi < 4; ++mi)
#pragma unroll
      for (int ni = 0; ni < 4; ++ni)
        acc[mi][ni] = mfma_bf16(af[mi], bfr[ni], acc[mi][ni]);
    __syncthreads();
  }

#pragma unroll
  for (int mi = 0; mi < 4; ++mi) {
#pragma unroll
    for (int ni = 0; ni < 4; ++ni) {
      const int r = row0 + wr * 64 + mi * 16 + (lane >> 4) * 4;
      const int c = col0 + wc * 64 + ni * 16 + (lane & 15);
#pragma unroll
      for (int j = 0; j < 4; ++j) {
        float v = acc[mi][ni][j];
        if (OUT_BF16)
          ((u16*)Cv)[(size_t)(r + j) * N + c] = f2bf(v);
        else
          ((float*)Cv)[(size_t)(r + j) * N + c] = v;
      }
    }
  }
}

// ---------------- RoPE (NeoX) in-place on q,k of qkv (bf16) ----------------
__global__ __launch_bounds__(256) void rope_kernel(u16* __restrict__ qkv) {
  int idx = blockIdx.x * 256 + threadIdx.x;  // T * 24 * 128
  int d = idx & 127;
  int hh = (idx >> 7) % 24;
  int t = idx / (24 * 128);
  if (t >= T_LEN) return;
  size_t base = (size_t)t * QKV_N + (hh < HN ? hh * DH : HN * DH + (hh - HN) * DH);
  float inv = exp2f((float)d * (-13.287712379549449f / 128.0f));  // 10000^(-d/128)
  float ang = (float)t * inv;
  float s = sinf(ang), c = cosf(ang);
  float x1 = bf2f(qkv[base + d]);
  float x2 = bf2f(qkv[base + d + 128]);
  qkv[base + d] = f2bf(x1 * c - x2 * s);
  qkv[base + d + 128] = f2bf(x2 * c + x1 * s);
}

// ---------------- V transpose: per (kvh, jtile) 32KB d-major swizzled image -
// Image layout (u16): img[d*64 + gr*8 + j] = V[jb + ((gr^(d&7))*8 + j)][d]
// so attn reads granule gr = q ^ (d&7) to get keys q*8..q*8+7 at dim d.
__global__ __launch_bounds__(256) void vtrans_kernel(const u16* __restrict__ qkv,
                                                     u16* __restrict__ vt) {
  __shared__ u16 tile[256 * 72];  // [d][t], stride 72
  const int jb = blockIdx.x * 64;
  const int kvh = blockIdx.y;
  const int tid = threadIdx.x;
  const int t = tid & 63, dc = tid >> 6;

  const u16* src = qkv + (size_t)(jb + t) * QKV_N + VOFF + kvh * DH + dc * 64;
#pragma unroll
  for (int i = 0; i < 8; ++i) {
    short8 v = *(const short8*)(src + i * 8);
    int d0 = dc * 64 + i * 8;
#pragma unroll
    for (int j = 0; j < 8; ++j) tile[(d0 + j) * 72 + t] = (u16)(short)v[j];
  }
  __syncthreads();

  u16* dst = vt + ((size_t)kvh * NJT + blockIdx.x) * 16384;
#pragma unroll
  for (int s = 0; s < 8; ++s) {
    int G = s * 256 + tid;            // granule index 0..2047
    int d = G >> 3, g = G & 7;
    short8 x = *(const short8*)&tile[d * 72 + ((g ^ (d & 7)) * 8)];
    *(short8*)(dst + G * 8) = x;
  }
}

// ---------------- flash attention, KV-split C=2, KVBLK=64 ----------------
// grid (48, 16, 2); 256 thr = 4 waves, wave w owns q rows qb+w*16..+15.
// K LDS: row-major [64][256] with 16B-granule XOR swizzle (g' = g ^ (row&7)).
// V LDS: pre-swizzled d-major image (from vtrans), staged linearly.
__global__ __launch_bounds__(256) void attn_kernel(const u16* __restrict__ qkv,
                                                   const u16* __restrict__ vt,
                                                   u16* __restrict__ po,
                                                   float* __restrict__ ml) {
  const int qt = blockIdx.x;
  const int h = blockIdx.y;
  const int c = blockIdx.z;
  const int qb = qt * 64;
  const int kvh = h >> 1;
  const int tid = threadIdx.x, lane = tid & 63, w = tid >> 6;

  __shared__ u16 sK[64 * 256];
  __shared__ u16 sVt[64 * 256];
  __shared__ u16 sP[4][16 * PSTR];

  int jmin = qb - WIN; if (jmin < 0) jmin = 0;
  const int jt0 = jmin >> 6, jt1 = qb >> 6;
  const int nt = jt1 - jt0 + 1;
  const int half = (nt + 1) >> 1;
  const int t_beg = (c == 0) ? jt0 : jt0 + half;
  const int t_end = (c == 0) ? jt0 + half : jt1 + 1;  // exclusive

  // Q fragments (row = lane&15, k-chunk base (lane>>4)*8)
  const int qrow = qb + w * 16 + (lane & 15);
  short8 qf[8];
  {
    const u16* qp = qkv + (size_t)qrow * QKV_N + h * DH + (lane >> 4) * 8;
#pragma unroll
    for (int kc = 0; kc < 8; ++kc) qf[kc] = *(const short8*)(qp + kc * 32);
  }

  f32x4 O[16];
#pragma unroll
  for (int i = 0; i < 16; ++i) O[i] = f32x4{0.f, 0.f, 0.f, 0.f};
  float mrow[4] = {-1e30f, -1e30f, -1e30f, -1e30f};
  float lrow[4] = {0.f, 0.f, 0.f, 0.f};

  // V fragment offsets (nf-independent part): d = nf*16 + (lane&15)
  const int dl = lane & 15;
  const int vb0 = dl * 64 + (((lane >> 4)) ^ (dl & 7)) * 8;
  const int vb1 = dl * 64 + (((lane >> 4) + 4) ^ (dl & 7)) * 8;

  for (int jt = t_beg; jt < t_end; ++jt) {
    const int jb = jt * 64;
    // ---- stage K [64][256], XOR-swizzled source, linear dest
#pragma unroll
    for (int i = 0; i < 8; ++i) {
      int rl = w * 16 + i * 2 + (lane >> 5);
      int g = (lane & 31) ^ (rl & 7);
      gload_lds16(qkv + (size_t)(jb + rl) * QKV_N + KOFF + kvh * DH + g * 8,
                  &sK[(w * 16 + i * 2) * 256]);
    }
    // ---- stage V image (linear copy of pre-swizzled global tile)
    {
      const u16* vtile = vt + ((size_t)kvh * NJT + jt) * 16384;
#pragma unroll
      for (int s = 0; s < 8; ++s) {
        int id = w * 8 + s;
        gload_lds16(vtile + id * 512 + lane * 8, &sVt[id * 512]);
      }
    }
    __syncthreads();

    // ---- S = Q K^T (16 q x 64 keys per wave, 4 col-frags)
    f32x4 S[4];
#pragma unroll
    for (int nf = 0; nf < 4; ++nf) S[nf] = f32x4{0.f, 0.f, 0.f, 0.f};
#pragma unroll
    for (int nf = 0; nf < 4; ++nf) {
      int krow = nf * 16 + (lane & 15);
#pragma unroll
      for (int kc = 0; kc < 8; ++kc) {
        int g = (kc * 4 + (lane >> 4)) ^ (krow & 7);
        short8 kf = *(const short8*)&sK[krow * 256 + g * 8];
        S[nf] = mfma_bf16(qf[kc], kf, S[nf]);
      }
    }

    // ---- softcap + mask + online softmax (row = (lane>>4)*4 + r)
#pragma unroll
    for (int r = 0; r < 4; ++r) {
      const int irow = qb + w * 16 + (lane >> 4) * 4 + r;
      float sv[4];
      float mx = -1e30f;
#pragma unroll
      for (int nf = 0; nf < 4; ++nf) {
        int j = jb + nf * 16 + (lane & 15);
        float x = S[nf][r] * (SCALING / SOFTCAP);
        float e2 = __expf(-2.0f * fabsf(x));
        float th = (1.0f - e2) / (1.0f + e2);
        th = x >= 0.0f ? th : -th;
        float val = SOFTCAP * th;
        bool ok = (j <= irow) && (irow - j <= WIN);
        sv[nf] = ok ? val : -1e30f;
        mx = fmaxf(mx, sv[nf]);
      }
#pragma unroll
      for (int off = 8; off >= 1; off >>= 1) mx = fmaxf(mx, __shfl_xor(mx, off));
      float mnew = fmaxf(mrow[r], mx);
      float alpha = (mrow[r] > -5e29f) ? __expf(mrow[r] - mnew) : 0.0f;
      float rs = 0.f;
      int ql = (lane >> 4) * 4 + r;
#pragma unroll
      for (int nf = 0; nf < 4; ++nf) {
        float e = (sv[nf] > -5e29f) ? __expf(sv[nf] - mnew) : 0.0f;
        rs += e;
        sP[w][ql * PSTR + nf * 16 + (lane & 15)] = f2bf(e);
      }
#pragma unroll
      for (int off = 8; off >= 1; off >>= 1) rs += __shfl_xor(rs, off);
      lrow[r] = lrow[r] * alpha + rs;
      mrow[r] = mnew;
#pragma unroll
      for (int q2 = 0; q2 < 16; ++q2) O[q2][r] *= alpha;
    }

    // ---- O += P V  (P A-frags from sP; V B-frags from swizzled image)
    short8 pf0 = *(const short8*)&sP[w][(lane & 15) * PSTR + (lane >> 4) * 8];
    short8 pf1 = *(const short8*)&sP[w][(lane & 15) * PSTR + 32 + (lane >> 4) * 8];
#pragma unroll
    for (int nf = 0; nf < 16; ++nf) {
      short8 vf0 = *(const short8*)&sVt[nf * 1024 + vb0];
      short8 vf1 = *(const short8*)&sVt[nf * 1024 + vb1];
      O[nf] = mfma_bf16(pf0, vf0, O[nf]);
      O[nf] = mfma_bf16(pf1, vf1, O[nf]);
    }
    __syncthreads();
  }

  // ---- store partials: PO[c][t][h][d] bf16 (raw O), ML[c][t][h][{m,l}] f32
#pragma unroll
  for (int nf = 0; nf < 16; ++nf) {
    int d = nf * 16 + (lane & 15);
#pragma unroll
    for (int r = 0; r < 4; ++r) {
      int trow = qb + w * 16 + (lane >> 4) * 4 + r;
      po[(((size_t)c * T_LEN + trow) * HN + h) * DH + d] = f2bf(O[nf][r]);
    }
  }
  if ((lane & 15) == 0) {
#pragma unroll
    for (int r = 0; r < 4; ++r) {
      int trow = qb + w * 16 + (lane >> 4) * 4 + r;
      size_t mi = (((size_t)c * T_LEN + trow) * HN + h) * 2;
      ml[mi] = mrow[r];
      ml[mi + 1] = lrow[r];
    }
  }
}

// ---------------- combine 2 partial chunks -> attnb (aliases PO chunk0) ----
__global__ __launch_bounds__(256) void combine_kernel(const u16* __restrict__ po,
                                                      const float* __restrict__ ml,
                                                      u16* __restrict__ attnb) {
  const int t = blockIdx.x;
  const int h = threadIdx.x >> 4;
  const int d0 = (threadIdx.x & 15) * 16;
  const size_t row = (size_t)t * HN + h;
  const float m0 = ml[row * 2], l0 = ml[row * 2 + 1];
  const float m1 = ml[(size_t)T_LEN * HN * 2 + row * 2];
  const float l1 = ml[(size_t)T_LEN * HN * 2 + row * 2 + 1];
  const float m = fmaxf(m0, m1);
  const float w0 = (m0 > -5e29f) ? __expf(m0 - m) : 0.f;
  const float w1 = (m1 > -5e29f) ? __expf(m1 - m) : 0.f;
  const float inv = 1.0f / (l0 * w0 + l1 * w1);
  const size_t i0 = row * DH + d0;
  const size_t i1 = (size_t)T_LEN * HN * DH + i0;
#pragma unroll
  for (int half = 0; half < 2; ++half) {
    short8 x0 = *(const short8*)(po + i0 + half * 8);
    short8 x1 = *(const short8*)(po + i1 + half * 8);
    short8 o;
#pragma unroll
    for (int j = 0; j < 8; ++j)
      o[j] = (short)f2bf((bf2f((u16)x0[j]) * w0 + bf2f((u16)x1[j]) * w1) * inv);
    *(short8*)(attnb + i0 + half * 8) = o;
  }
}

// ---------------- host launcher ----------------
extern "C" void kernel_launch(void* const* d_in, const int* in_sizes, int n_in,
                              void* d_out, int out_size, void* d_ws, size_t ws_size,
                              hipStream_t stream) {
  const float* hidden = (const float*)d_in[1];
  const float* w_qkv = (const float*)d_in[2];
  const float* w_o = (const float*)d_in[3];
  float* out = (float*)d_out;
  char* ws = (char*)d_ws;

  // Layout (peak 131,072,000 B):
  //  [0, 58,720,256):           wqkvb -> after GEMM1: PO[2] (50.3M) + ML (0.8M)
  //  [58,720,256, 80,740,352):  hb    -> after GEMM1: Vt (12.6M)
  //  [80,740,352, 131,072,000): qkvb  -> after attn:  wob (29.4M)
  u16* wqkvb = (u16*)(ws);
  u16* po = (u16*)(ws);                        // [2][T][H][256] bf16
  float* ml = (float*)(ws + 50331648);         // [2][T][H][2] f32
  u16* attnb = (u16*)(ws);                     // aliases PO0
  u16* hb = (u16*)(ws + 58720256);
  u16* vtb = (u16*)(ws + 58720256);            // aliases hb (dead after GEMM1)
  u16* qkvb = (u16*)(ws + 80740352);
  u16* wob = (u16*)(ws + 80740352);

  {
    int n = T_LEN * HID;
    cvt_kernel<<<dim3((n / 4 + 255) / 256), 256, 0, stream>>>(hidden, hb, n);
  }
  {
    int n = QKV_N * HID;
    cvt_kernel<<<dim3((n / 4 + 255) / 256), 256, 0, stream>>>(w_qkv, wqkvb, n);
  }
  gemm_bt<1><<<dim3(24 * 64), 256, 0, stream>>>(hb, wqkvb, qkvb, T_LEN, QKV_N, HID, 64);
  {
    int n = T_LEN * 24 * 128;
    rope_kernel<<<dim3(n / 256), 256, 0, stream>>>(qkvb);
  }
  vtrans_kernel<<<dim3(NJT, KVH), 256, 0, stream>>>(qkvb, vtb);
  attn_kernel<<<dim3(T_LEN / 64, HN, 2), 256, 0, stream>>>(qkvb, vtb, po, ml);
  {
    int n = HID * O_N;  // w_o conversion AFTER attn (overwrites qkvb region)
    cvt_kernel<<<dim3((n / 4 + 255) / 256), 256, 0, stream>>>(w_o, wob, n);
  }
  combine_kernel<<<dim3(T_LEN), 256, 0, stream>>>(po, ml, attnb);
  gemm_bt<0><<<dim3(24 * 28), 256, 0, stream>>>(attnb, wob, out, T_LEN, HID, O_N, 28);
}

// Round 4
// 630.316 us; speedup vs baseline: 1.4149x; 1.1976x over previous
//
#include <hip/hip_runtime.h>
#include <math.h>

typedef unsigned short u16;
typedef __attribute__((ext_vector_type(8))) short short8;
typedef __attribute__((ext_vector_type(4))) float f32x4;
typedef __attribute__((ext_vector_type(4))) unsigned short u16x4;

#define HN 16
#define KVH 8
#define DH 256
#define HID 3584
#define T_LEN 3072
#define QKV_N 8192   // H*D + 2*KV*D
#define O_N 4096     // H*D
#define WIN 1535
#define SCALING 0.0625f
#define SOFTCAP 50.0f
#define KOFF 4096    // HN*DH
#define VOFF 6144    // HN*DH + KVH*DH
#define PSTR 72
#define NJT 48       // T_LEN/64
#define M_FIX 20.0f  // fixed softmax max; valid because softcap bounds |s|<=50

__device__ __forceinline__ u16 f2bf(float f) {
  unsigned u = __float_as_uint(f);
  u += 0x7FFFu + ((u >> 16) & 1u);
  return (u16)(u >> 16);
}
__device__ __forceinline__ float bf2f(u16 b) {
  return __uint_as_float(((unsigned)b) << 16);
}

__device__ __forceinline__ void gload_lds16(const void* g, void* l) {
  __builtin_amdgcn_global_load_lds(
      (const __attribute__((address_space(1))) void*)g,
      (__attribute__((address_space(3))) void*)l, 16, 0, 0);
}

__device__ __forceinline__ f32x4 mfma_bf16(short8 a, short8 b, f32x4 c) {
  return __builtin_amdgcn_mfma_f32_16x16x32_bf16(a, b, c, 0, 0, 0);
}

// ---------------- f32 -> bf16 convert (n % 4 == 0) ----------------
__global__ __launch_bounds__(256) void cvt_kernel(const float* __restrict__ in,
                                                  u16* __restrict__ out, int n) {
  int i = (blockIdx.x * 256 + threadIdx.x) * 4;
  if (i >= n) return;
  float4 v = *(const float4*)(in + i);
  u16x4 o;
  o[0] = f2bf(v.x); o[1] = f2bf(v.y); o[2] = f2bf(v.z); o[3] = f2bf(v.w);
  *(u16x4*)(out + i) = o;
}

// ---------------- GEMM: C[M,N] = A[M,K] * B[N,K]^T  (m97 structure) ---------
template <int OUT_BF16>
__global__ __launch_bounds__(256) void gemm_bt(const u16* __restrict__ A,
                                               const u16* __restrict__ B,
                                               void* __restrict__ Cv,
                                               int M, int N, int K, int ntn) {
  __shared__ u16 sA[128 * 32];
  __shared__ u16 sB[128 * 32];
  const int bm = blockIdx.x / ntn, bn = blockIdx.x % ntn;
  const int row0 = bm * 128, col0 = bn * 128;
  const int tid = threadIdx.x, lane = tid & 63, w = tid >> 6;
  const int wr = w >> 1, wc = w & 1;
  f32x4 acc[4][4] = {};
  (void)M;

  const u16* Abase = A + (size_t)(row0 + w * 32 + (lane >> 2)) * K + (lane & 3) * 8;
  const u16* Bbase = B + (size_t)(col0 + w * 32 + (lane >> 2)) * K + (lane & 3) * 8;
  u16* sAdst = &sA[w * 32 * 32];
  u16* sBdst = &sB[w * 32 * 32];

  for (int k0 = 0; k0 < K; k0 += 32) {
    gload_lds16(Abase + k0, sAdst);
    gload_lds16(Abase + k0 + (size_t)16 * K, sAdst + 16 * 32);
    gload_lds16(Bbase + k0, sBdst);
    gload_lds16(Bbase + k0 + (size_t)16 * K, sBdst + 16 * 32);
    __syncthreads();

    short8 af[4], bfr[4];
#pragma unroll
    for (int mi = 0; mi < 4; ++mi)
      af[mi] = *(const short8*)&sA[(wr * 64 + mi * 16 + (lane & 15)) * 32 + (lane >> 4) * 8];
#pragma unroll
    for (int ni = 0; ni < 4; ++ni)
      bfr[ni] = *(const short8*)&sB[(wc * 64 + ni * 16 + (lane & 15)) * 32 + (lane >> 4) * 8];
#pragma unroll
    for (int mi = 0; mi < 4; ++mi)
#pragma unroll
      for (int ni = 0; ni < 4; ++ni)
        acc[mi][ni] = mfma_bf16(af[mi], bfr[ni], acc[mi][ni]);
    __syncthreads();
  }

#pragma unroll
  for (int mi = 0; mi < 4; ++mi) {
#pragma unroll
    for (int ni = 0; ni < 4; ++ni) {
      const int r = row0 + wr * 64 + mi * 16 + (lane >> 4) * 4;
      const int c = col0 + wc * 64 + ni * 16 + (lane & 15);
#pragma unroll
      for (int j = 0; j < 4; ++j) {
        float v = acc[mi][ni][j];
        if (OUT_BF16)
          ((u16*)Cv)[(size_t)(r + j) * N + c] = f2bf(v);
        else
          ((float*)Cv)[(size_t)(r + j) * N + c] = v;
      }
    }
  }
}

// ---------------- RoPE (NeoX) in-place on q,k of qkv (bf16) ----------------
__global__ __launch_bounds__(256) void rope_kernel(u16* __restrict__ qkv) {
  int idx = blockIdx.x * 256 + threadIdx.x;  // T * 24 * 128
  int d = idx & 127;
  int hh = (idx >> 7) % 24;
  int t = idx / (24 * 128);
  if (t >= T_LEN) return;
  size_t base = (size_t)t * QKV_N + (hh < HN ? hh * DH : HN * DH + (hh - HN) * DH);
  float inv = exp2f((float)d * (-13.287712379549449f / 128.0f));  // 10000^(-d/128)
  float ang = (float)t * inv;
  float s = sinf(ang), c = cosf(ang);
  float x1 = bf2f(qkv[base + d]);
  float x2 = bf2f(qkv[base + d + 128]);
  qkv[base + d] = f2bf(x1 * c - x2 * s);
  qkv[base + d + 128] = f2bf(x2 * c + x1 * s);
}

// ---------------- V transpose: per (kvh, jtile) 32KB d-major swizzled image -
// Image layout (u16): img[d*64 + gr*8 + j] = V[jb + ((gr^(d&7))*8 + j)][d]
__global__ __launch_bounds__(256) void vtrans_kernel(const u16* __restrict__ qkv,
                                                     u16* __restrict__ vt) {
  __shared__ u16 tile[256 * 72];  // [d][t], stride 72
  const int jb = blockIdx.x * 64;
  const int kvh = blockIdx.y;
  const int tid = threadIdx.x;
  const int t = tid & 63, dc = tid >> 6;

  const u16* src = qkv + (size_t)(jb + t) * QKV_N + VOFF + kvh * DH + dc * 64;
#pragma unroll
  for (int i = 0; i < 8; ++i) {
    short8 v = *(const short8*)(src + i * 8);
    int d0 = dc * 64 + i * 8;
#pragma unroll
    for (int j = 0; j < 8; ++j) tile[(d0 + j) * 72 + t] = (u16)(short)v[j];
  }
  __syncthreads();

  u16* dst = vt + ((size_t)kvh * NJT + blockIdx.x) * 16384;
#pragma unroll
  for (int s = 0; s < 8; ++s) {
    int G = s * 256 + tid;            // granule index 0..2047
    int d = G >> 3, g = G & 7;
    short8 x = *(const short8*)&tile[d * 72 + ((g ^ (d & 7)) * 8)];
    *(short8*)(dst + G * 8) = x;
  }
}

// ---------------- flash attention, KV-split C=2, KVBLK=64, fixed-max -------
// 1D grid 1536, wgid constructed so wgid%8 == kvh -> same-kvh blocks share an
// XCD (3MB K+V working set fits the 4MB per-XCD L2).
// K LDS: row-major [64][256], 16B-granule XOR swizzle (g' = g ^ (row&7)).
// V LDS: pre-swizzled d-major image (from vtrans), staged linearly.
__global__ __launch_bounds__(256) void attn_kernel(const u16* __restrict__ qkv,
                                                   const u16* __restrict__ vt,
                                                   u16* __restrict__ po,
                                                   float* __restrict__ ml) {
  const int wg = blockIdx.x;
  const int kvh = wg & 7;
  const int rest = wg >> 3;
  const int qt = rest >> 2;
  const int c = (rest >> 1) & 1;
  const int h = kvh * 2 + (rest & 1);
  const int qb = qt * 64;
  const int tid = threadIdx.x, lane = tid & 63, w = tid >> 6;

  __shared__ u16 sK[64 * 256];
  __shared__ u16 sVt[64 * 256];
  __shared__ u16 sP[4][16 * PSTR];

  int jmin = qb - WIN; if (jmin < 0) jmin = 0;
  const int jt0 = jmin >> 6, jt1 = qb >> 6;
  const int nt = jt1 - jt0 + 1;
  const int half = (nt + 1) >> 1;
  const int t_beg = (c == 0) ? jt0 : jt0 + half;
  const int t_end = (c == 0) ? jt0 + half : jt1 + 1;  // exclusive

  // Q fragments (row = lane&15, k-chunk base (lane>>4)*8)
  const int qrow = qb + w * 16 + (lane & 15);
  short8 qf[8];
  {
    const u16* qp = qkv + (size_t)qrow * QKV_N + h * DH + (lane >> 4) * 8;
#pragma unroll
    for (int kc = 0; kc < 8; ++kc) qf[kc] = *(const short8*)(qp + kc * 32);
  }

  f32x4 O[16];
#pragma unroll
  for (int i = 0; i < 16; ++i) O[i] = f32x4{0.f, 0.f, 0.f, 0.f};
  float lrow[4] = {0.f, 0.f, 0.f, 0.f};  // per-lane partial sums (reduced at end)

  // V fragment offsets (nf-independent part): d = nf*16 + (lane&15)
  const int dl = lane & 15;
  const int vb0 = dl * 64 + (((lane >> 4)) ^ (dl & 7)) * 8;
  const int vb1 = dl * 64 + (((lane >> 4) + 4) ^ (dl & 7)) * 8;

  for (int jt = t_beg; jt < t_end; ++jt) {
    const int jb = jt * 64;
    // ---- stage K [64][256], XOR-swizzled source, linear dest
#pragma unroll
    for (int i = 0; i < 8; ++i) {
      int rl = w * 16 + i * 2 + (lane >> 5);
      int g = (lane & 31) ^ (rl & 7);
      gload_lds16(qkv + (size_t)(jb + rl) * QKV_N + KOFF + kvh * DH + g * 8,
                  &sK[(w * 16 + i * 2) * 256]);
    }
    // ---- stage V image (linear copy of pre-swizzled global tile)
    {
      const u16* vtile = vt + ((size_t)kvh * NJT + jt) * 16384;
#pragma unroll
      for (int s = 0; s < 8; ++s) {
        int id = w * 8 + s;
        gload_lds16(vtile + id * 512 + lane * 8, &sVt[id * 512]);
      }
    }
    __syncthreads();

    // ---- S = Q K^T (16 q x 64 keys per wave, 4 col-frags)
    f32x4 S[4];
#pragma unroll
    for (int nf = 0; nf < 4; ++nf) S[nf] = f32x4{0.f, 0.f, 0.f, 0.f};
#pragma unroll
    for (int nf = 0; nf < 4; ++nf) {
      int krow = nf * 16 + (lane & 15);
#pragma unroll
      for (int kc = 0; kc < 8; ++kc) {
        int g = (kc * 4 + (lane >> 4)) ^ (krow & 7);
        short8 kf = *(const short8*)&sK[krow * 256 + g * 8];
        S[nf] = mfma_bf16(qf[kc], kf, S[nf]);
      }
    }

    // ---- softcap + mask + fixed-max softmax (row = (lane>>4)*4 + r)
    // No cross-lane ops, no O-rescale: p = exp(s - M_FIX), l accumulated
    // per-lane and reduced once at the end.
#pragma unroll
    for (int r = 0; r < 4; ++r) {
      const int irow = qb + w * 16 + (lane >> 4) * 4 + r;
      const int ql = (lane >> 4) * 4 + r;
#pragma unroll
      for (int nf = 0; nf < 4; ++nf) {
        int j = jb + nf * 16 + (lane & 15);
        float x = S[nf][r] * (SCALING / SOFTCAP);
        float e2 = __expf(-2.0f * fabsf(x));
        float th = (1.0f - e2) / (1.0f + e2);
        th = x >= 0.0f ? th : -th;
        float val = SOFTCAP * th;
        bool ok = (j <= irow) && (irow - j <= WIN);
        float p = ok ? __expf(val - M_FIX) : 0.0f;
        lrow[r] += p;
        sP[w][ql * PSTR + nf * 16 + (lane & 15)] = f2bf(p);
      }
    }

    // ---- O += P V  (P A-frags from sP; V B-frags from swizzled image)
    short8 pf0 = *(const short8*)&sP[w][(lane & 15) * PSTR + (lane >> 4) * 8];
    short8 pf1 = *(const short8*)&sP[w][(lane & 15) * PSTR + 32 + (lane >> 4) * 8];
#pragma unroll
    for (int nf = 0; nf < 16; ++nf) {
      short8 vf0 = *(const short8*)&sVt[nf * 1024 + vb0];
      short8 vf1 = *(const short8*)&sVt[nf * 1024 + vb1];
      O[nf] = mfma_bf16(pf0, vf0, O[nf]);
      O[nf] = mfma_bf16(pf1, vf1, O[nf]);
    }
    __syncthreads();
  }

  // ---- final l reduction across the 16-lane column groups
#pragma unroll
  for (int r = 0; r < 4; ++r) {
#pragma unroll
    for (int off = 8; off >= 1; off >>= 1) lrow[r] += __shfl_xor(lrow[r], off);
  }

  // ---- store partials: PO[c][t][h][d] bf16 (raw O), ML[c][t][h][{m,l}] f32
#pragma unroll
  for (int nf = 0; nf < 16; ++nf) {
    int d = nf * 16 + (lane & 15);
#pragma unroll
    for (int r = 0; r < 4; ++r) {
      int trow = qb + w * 16 + (lane >> 4) * 4 + r;
      po[(((size_t)c * T_LEN + trow) * HN + h) * DH + d] = f2bf(O[nf][r]);
    }
  }
  if ((lane & 15) == 0) {
#pragma unroll
    for (int r = 0; r < 4; ++r) {
      int trow = qb + w * 16 + (lane >> 4) * 4 + r;
      size_t mi = (((size_t)c * T_LEN + trow) * HN + h) * 2;
      ml[mi] = M_FIX;
      ml[mi + 1] = lrow[r];
    }
  }
}

// ---------------- combine 2 partial chunks -> attnb (aliases PO chunk0) ----
// Fixed-max partials: O = (O0 + O1) / (l0 + l1).
__global__ __launch_bounds__(256) void combine_kernel(const u16* __restrict__ po,
                                                      const float* __restrict__ ml,
                                                      u16* __restrict__ attnb) {
  const int t = blockIdx.x;
  const int h = threadIdx.x >> 4;
  const int d0 = (threadIdx.x & 15) * 16;
  const size_t row = (size_t)t * HN + h;
  const float l0 = ml[row * 2 + 1];
  const float l1 = ml[(size_t)T_LEN * HN * 2 + row * 2 + 1];
  const float inv = 1.0f / (l0 + l1);
  const size_t i0 = row * DH + d0;
  const size_t i1 = (size_t)T_LEN * HN * DH + i0;
#pragma unroll
  for (int half = 0; half < 2; ++half) {
    short8 x0 = *(const short8*)(po + i0 + half * 8);
    short8 x1 = *(const short8*)(po + i1 + half * 8);
    short8 o;
#pragma unroll
    for (int j = 0; j < 8; ++j)
      o[j] = (short)f2bf((bf2f((u16)x0[j]) + bf2f((u16)x1[j])) * inv);
    *(short8*)(attnb + i0 + half * 8) = o;
  }
}

// ---------------- host launcher ----------------
extern "C" void kernel_launch(void* const* d_in, const int* in_sizes, int n_in,
                              void* d_out, int out_size, void* d_ws, size_t ws_size,
                              hipStream_t stream) {
  const float* hidden = (const float*)d_in[1];
  const float* w_qkv = (const float*)d_in[2];
  const float* w_o = (const float*)d_in[3];
  float* out = (float*)d_out;
  char* ws = (char*)d_ws;

  // Layout (peak 131,072,000 B):
  //  [0, 58,720,256):           wqkvb -> after GEMM1: PO[2] (50.3M) + ML (0.8M)
  //  [58,720,256, 80,740,352):  hb    -> after GEMM1: Vt (12.6M)
  //  [80,740,352, 131,072,000): qkvb  -> after attn:  wob (29.4M)
  u16* wqkvb = (u16*)(ws);
  u16* po = (u16*)(ws);                        // [2][T][H][256] bf16
  float* ml = (float*)(ws + 50331648);         // [2][T][H][2] f32
  u16* attnb = (u16*)(ws);                     // aliases PO0
  u16* hb = (u16*)(ws + 58720256);
  u16* vtb = (u16*)(ws + 58720256);            // aliases hb (dead after GEMM1)
  u16* qkvb = (u16*)(ws + 80740352);
  u16* wob = (u16*)(ws + 80740352);

  {
    int n = T_LEN * HID;
    cvt_kernel<<<dim3((n / 4 + 255) / 256), 256, 0, stream>>>(hidden, hb, n);
  }
  {
    int n = QKV_N * HID;
    cvt_kernel<<<dim3((n / 4 + 255) / 256), 256, 0, stream>>>(w_qkv, wqkvb, n);
  }
  gemm_bt<1><<<dim3(24 * 64), 256, 0, stream>>>(hb, wqkvb, qkvb, T_LEN, QKV_N, HID, 64);
  {
    int n = T_LEN * 24 * 128;
    rope_kernel<<<dim3(n / 256), 256, 0, stream>>>(qkvb);
  }
  vtrans_kernel<<<dim3(NJT, KVH), 256, 0, stream>>>(qkvb, vtb);
  attn_kernel<<<dim3(1536), 256, 0, stream>>>(qkvb, vtb, po, ml);
  {
    int n = HID * O_N;  // w_o conversion AFTER attn (overwrites qkvb region)
    cvt_kernel<<<dim3((n / 4 + 255) / 256), 256, 0, stream>>>(w_o, wob, n);
  }
  combine_kernel<<<dim3(T_LEN), 256, 0, stream>>>(po, ml, attnb);
  gemm_bt<0><<<dim3(24 * 28), 256, 0, stream>>>(attnb, wob, out, T_LEN, HID, O_N, 28);
}

// Round 5
// 583.174 us; speedup vs baseline: 1.5292x; 1.0808x over previous
//
#include <hip/hip_runtime.h>
#include <math.h>

typedef unsigned short u16;
typedef __attribute__((ext_vector_type(8))) short short8;
typedef __attribute__((ext_vector_type(4))) float f32x4;
typedef __attribute__((ext_vector_type(4))) unsigned short u16x4;

#define HN 16
#define KVH 8
#define DH 256
#define HID 3584
#define T_LEN 3072
#define QKV_N 8192   // H*D + 2*KV*D
#define O_N 4096     // H*D
#define WIN 1535
#define SCALING 0.0625f
#define SOFTCAP 50.0f
#define KOFF 4096    // HN*DH
#define VOFF 6144    // HN*DH + KVH*DH
#define PSTR 72
#define NJT 48       // T_LEN/64
#define M_FIX 20.0f  // fixed softmax max; valid because softcap bounds |s|<=50

__device__ __forceinline__ u16 f2bf(float f) {
  unsigned u = __float_as_uint(f);
  u += 0x7FFFu + ((u >> 16) & 1u);
  return (u16)(u >> 16);
}
__device__ __forceinline__ float bf2f(u16 b) {
  return __uint_as_float(((unsigned)b) << 16);
}

__device__ __forceinline__ void gload_lds16(const void* g, void* l) {
  __builtin_amdgcn_global_load_lds(
      (const __attribute__((address_space(1))) void*)g,
      (__attribute__((address_space(3))) void*)l, 16, 0, 0);
}

__device__ __forceinline__ f32x4 mfma_bf16(short8 a, short8 b, f32x4 c) {
  return __builtin_amdgcn_mfma_f32_16x16x32_bf16(a, b, c, 0, 0, 0);
}

// ---------------- f32 -> bf16 convert (n % 4 == 0) ----------------
__global__ __launch_bounds__(256) void cvt_kernel(const float* __restrict__ in,
                                                  u16* __restrict__ out, int n) {
  int i = (blockIdx.x * 256 + threadIdx.x) * 4;
  if (i >= n) return;
  float4 v = *(const float4*)(in + i);
  u16x4 o;
  o[0] = f2bf(v.x); o[1] = f2bf(v.y); o[2] = f2bf(v.z); o[3] = f2bf(v.w);
  *(u16x4*)(out + i) = o;
}

// ---------------- GEMM 256x256, BK=64, counted-vmcnt pipeline --------------
// C[M,N] = A[M,K] * B[N,K]^T, all tiles exact multiples (no bounds checks).
// 512 thr = 8 waves (2 Mx4 N); per-wave 128x64 output = acc[8][4].
// LDS: 2 dbuf x (A 256x64 + B 256x64) bf16 = 128 KiB, linear rows,
// granule-XOR swizzle (g' = g ^ (row&7)) applied on the global SOURCE at
// staging and on ds_read addresses -> even 8-access/bank b128 reads.
// Pipeline: issue tile t+1's 8 loads -> vmcnt(8) (tile t certified, t+1 in
// flight across the barrier) -> s_barrier -> 64 MFMA -> s_barrier.
template <int OUT_BF16>
__global__ __launch_bounds__(512, 2) void gemm8(const u16* __restrict__ A,
                                                const u16* __restrict__ B,
                                                void* __restrict__ Cv,
                                                int N, int K, int ntn, int cpx) {
  __shared__ u16 sA[2][256 * 64];
  __shared__ u16 sB[2][256 * 64];

  const int bid = blockIdx.x;
  const int wg = (bid & 7) * cpx + (bid >> 3);  // XCD swizzle (nwg%8==0)
  const int bm = wg / ntn, bn = wg % ntn;
  const int row0 = bm * 256, col0 = bn * 256;
  const int tid = threadIdx.x, lane = tid & 63, wid = tid >> 6;
  const int wr = wid >> 2, wc = wid & 3;

  // staging: chunk c = wid*4+i covers tile rows [c*8, c*8+8); lane l writes
  // LDS row c*8+(l>>3), granule l&7, which must hold global granule
  // (l&7)^(l>>3)  (inverse-swizzled source).
  const int srow = lane >> 3;
  const int sg = (lane & 7) ^ srow;
  const u16* Asrc = A + (size_t)(row0 + wid * 32 + srow) * K + sg * 8;
  const u16* Bsrc = B + (size_t)(col0 + wid * 32 + srow) * K + sg * 8;
  const size_t rK8 = (size_t)8 * K;

  f32x4 acc[8][4] = {};
  const int NT = K >> 6;

  // prologue: stage tile 0 into dbuf 0
#pragma unroll
  for (int i = 0; i < 4; ++i) {
    gload_lds16(Asrc + i * rK8, &sA[0][(wid * 4 + i) * 512]);
    gload_lds16(Bsrc + i * rK8, &sB[0][(wid * 4 + i) * 512]);
  }

  const int fr = lane & 15;
  const int g0 = (lane >> 4) ^ (lane & 7);        // kk=0 granule
  const int g1 = (4 + (lane >> 4)) ^ (lane & 7);  // kk=1 granule

  for (int t = 0; t < NT; ++t) {
    const int d = t & 1;
    if (t + 1 < NT) {
      const u16* As = Asrc + (size_t)(t + 1) * 64;
      const u16* Bs = Bsrc + (size_t)(t + 1) * 64;
#pragma unroll
      for (int i = 0; i < 4; ++i) {
        gload_lds16(As + i * rK8, &sA[d ^ 1][(wid * 4 + i) * 512]);
        gload_lds16(Bs + i * rK8, &sB[d ^ 1][(wid * 4 + i) * 512]);
      }
      __builtin_amdgcn_sched_barrier(0);
      asm volatile("s_waitcnt vmcnt(8)" ::: "memory");
    } else {
      asm volatile("s_waitcnt vmcnt(0)" ::: "memory");
    }
    __builtin_amdgcn_sched_barrier(0);
    __builtin_amdgcn_s_barrier();
    __builtin_amdgcn_sched_barrier(0);

    __builtin_amdgcn_s_setprio(1);
#pragma unroll
    for (int kk = 0; kk < 2; ++kk) {
      const int gk = kk ? g1 : g0;
      short8 af[8];
#pragma unroll
      for (int mi = 0; mi < 8; ++mi)
        af[mi] = *(const short8*)&sA[d][(wr * 128 + mi * 16 + fr) * 64 + gk * 8];
#pragma unroll
      for (int nh = 0; nh < 2; ++nh) {
        short8 bf[2];
#pragma unroll
        for (int nb = 0; nb < 2; ++nb)
          bf[nb] = *(const short8*)&sB[d][(wc * 64 + (nh * 2 + nb) * 16 + fr) * 64 + gk * 8];
#pragma unroll
        for (int mi = 0; mi < 8; ++mi)
#pragma unroll
          for (int nb = 0; nb < 2; ++nb)
            acc[mi][nh * 2 + nb] = mfma_bf16(af[mi], bf[nb], acc[mi][nh * 2 + nb]);
      }
    }
    __builtin_amdgcn_s_setprio(0);
    __builtin_amdgcn_sched_barrier(0);
    __builtin_amdgcn_s_barrier();
    __builtin_amdgcn_sched_barrier(0);
  }

  // epilogue: C write (C/D layout: col=lane&15, row=(lane>>4)*4+j)
#pragma unroll
  for (int mi = 0; mi < 8; ++mi) {
#pragma unroll
    for (int ni = 0; ni < 4; ++ni) {
      const int r = row0 + wr * 128 + mi * 16 + (lane >> 4) * 4;
      const int c = col0 + wc * 64 + ni * 16 + (lane & 15);
#pragma unroll
      for (int j = 0; j < 4; ++j) {
        float v = acc[mi][ni][j];
        if (OUT_BF16)
          ((u16*)Cv)[(size_t)(r + j) * N + c] = f2bf(v);
        else
          ((float*)Cv)[(size_t)(r + j) * N + c] = v;
      }
    }
  }
}

// ---------------- RoPE (NeoX) in-place on q,k of qkv (bf16) ----------------
__global__ __launch_bounds__(256) void rope_kernel(u16* __restrict__ qkv) {
  int idx = blockIdx.x * 256 + threadIdx.x;  // T * 24 * 128
  int d = idx & 127;
  int hh = (idx >> 7) % 24;
  int t = idx / (24 * 128);
  if (t >= T_LEN) return;
  size_t base = (size_t)t * QKV_N + (hh < HN ? hh * DH : HN * DH + (hh - HN) * DH);
  float inv = exp2f((float)d * (-13.287712379549449f / 128.0f));  // 10000^(-d/128)
  float ang = (float)t * inv;
  float s = sinf(ang), c = cosf(ang);
  float x1 = bf2f(qkv[base + d]);
  float x2 = bf2f(qkv[base + d + 128]);
  qkv[base + d] = f2bf(x1 * c - x2 * s);
  qkv[base + d + 128] = f2bf(x2 * c + x1 * s);
}

// ---------------- V transpose: per (kvh, jtile) 32KB d-major swizzled image -
// Image layout (u16): img[d*64 + gr*8 + j] = V[jb + ((gr^(d&7))*8 + j)][d]
__global__ __launch_bounds__(256) void vtrans_kernel(const u16* __restrict__ qkv,
                                                     u16* __restrict__ vt) {
  __shared__ u16 tile[256 * 72];  // [d][t], stride 72
  const int jb = blockIdx.x * 64;
  const int kvh = blockIdx.y;
  const int tid = threadIdx.x;
  const int t = tid & 63, dc = tid >> 6;

  const u16* src = qkv + (size_t)(jb + t) * QKV_N + VOFF + kvh * DH + dc * 64;
#pragma unroll
  for (int i = 0; i < 8; ++i) {
    short8 v = *(const short8*)(src + i * 8);
    int d0 = dc * 64 + i * 8;
#pragma unroll
    for (int j = 0; j < 8; ++j) tile[(d0 + j) * 72 + t] = (u16)(short)v[j];
  }
  __syncthreads();

  u16* dst = vt + ((size_t)kvh * NJT + blockIdx.x) * 16384;
#pragma unroll
  for (int s = 0; s < 8; ++s) {
    int G = s * 256 + tid;            // granule index 0..2047
    int d = G >> 3, g = G & 7;
    short8 x = *(const short8*)&tile[d * 72 + ((g ^ (d & 7)) * 8)];
    *(short8*)(dst + G * 8) = x;
  }
}

// ---------------- flash attention, KV-split C=2, KVBLK=64, fixed-max -------
// 1D grid 1536, wgid constructed so wgid%8 == kvh -> same-kvh blocks share an
// XCD (3MB K+V working set fits the 4MB per-XCD L2).
// K LDS: row-major [64][256], 16B-granule XOR swizzle (g' = g ^ (row&7)).
// V LDS: pre-swizzled d-major image (from vtrans), staged linearly.
__global__ __launch_bounds__(256) void attn_kernel(const u16* __restrict__ qkv,
                                                   const u16* __restrict__ vt,
                                                   u16* __restrict__ po,
                                                   float* __restrict__ ml) {
  const int wg = blockIdx.x;
  const int kvh = wg & 7;
  const int rest = wg >> 3;
  const int qt = rest >> 2;
  const int c = (rest >> 1) & 1;
  const int h = kvh * 2 + (rest & 1);
  const int qb = qt * 64;
  const int tid = threadIdx.x, lane = tid & 63, w = tid >> 6;

  __shared__ u16 sK[64 * 256];
  __shared__ u16 sVt[64 * 256];
  __shared__ u16 sP[4][16 * PSTR];

  int jmin = qb - WIN; if (jmin < 0) jmin = 0;
  const int jt0 = jmin >> 6, jt1 = qb >> 6;
  const int nt = jt1 - jt0 + 1;
  const int half = (nt + 1) >> 1;
  const int t_beg = (c == 0) ? jt0 : jt0 + half;
  const int t_end = (c == 0) ? jt0 + half : jt1 + 1;  // exclusive

  // Q fragments (row = lane&15, k-chunk base (lane>>4)*8)
  const int qrow = qb + w * 16 + (lane & 15);
  short8 qf[8];
  {
    const u16* qp = qkv + (size_t)qrow * QKV_N + h * DH + (lane >> 4) * 8;
#pragma unroll
    for (int kc = 0; kc < 8; ++kc) qf[kc] = *(const short8*)(qp + kc * 32);
  }

  f32x4 O[16];
#pragma unroll
  for (int i = 0; i < 16; ++i) O[i] = f32x4{0.f, 0.f, 0.f, 0.f};
  float lrow[4] = {0.f, 0.f, 0.f, 0.f};  // per-lane partial sums (reduced at end)

  // V fragment offsets (nf-independent part): d = nf*16 + (lane&15)
  const int dl = lane & 15;
  const int vb0 = dl * 64 + (((lane >> 4)) ^ (dl & 7)) * 8;
  const int vb1 = dl * 64 + (((lane >> 4) + 4) ^ (dl & 7)) * 8;

  for (int jt = t_beg; jt < t_end; ++jt) {
    const int jb = jt * 64;
    // ---- stage K [64][256], XOR-swizzled source, linear dest
#pragma unroll
    for (int i = 0; i < 8; ++i) {
      int rl = w * 16 + i * 2 + (lane >> 5);
      int g = (lane & 31) ^ (rl & 7);
      gload_lds16(qkv + (size_t)(jb + rl) * QKV_N + KOFF + kvh * DH + g * 8,
                  &sK[(w * 16 + i * 2) * 256]);
    }
    // ---- stage V image (linear copy of pre-swizzled global tile)
    {
      const u16* vtile = vt + ((size_t)kvh * NJT + jt) * 16384;
#pragma unroll
      for (int s = 0; s < 8; ++s) {
        int id = w * 8 + s;
        gload_lds16(vtile + id * 512 + lane * 8, &sVt[id * 512]);
      }
    }
    __syncthreads();

    // ---- S = Q K^T (16 q x 64 keys per wave, 4 col-frags)
    f32x4 S[4];
#pragma unroll
    for (int nf = 0; nf < 4; ++nf) S[nf] = f32x4{0.f, 0.f, 0.f, 0.f};
#pragma unroll
    for (int nf = 0; nf < 4; ++nf) {
      int krow = nf * 16 + (lane & 15);
#pragma unroll
      for (int kc = 0; kc < 8; ++kc) {
        int g = (kc * 4 + (lane >> 4)) ^ (krow & 7);
        short8 kf = *(const short8*)&sK[krow * 256 + g * 8];
        S[nf] = mfma_bf16(qf[kc], kf, S[nf]);
      }
    }

    // ---- softcap + mask + fixed-max softmax (row = (lane>>4)*4 + r)
#pragma unroll
    for (int r = 0; r < 4; ++r) {
      const int irow = qb + w * 16 + (lane >> 4) * 4 + r;
      const int ql = (lane >> 4) * 4 + r;
#pragma unroll
      for (int nf = 0; nf < 4; ++nf) {
        int j = jb + nf * 16 + (lane & 15);
        float x = S[nf][r] * (SCALING / SOFTCAP);
        float e2 = __expf(-2.0f * fabsf(x));
        float th = (1.0f - e2) / (1.0f + e2);
        th = x >= 0.0f ? th : -th;
        float val = SOFTCAP * th;
        bool ok = (j <= irow) && (irow - j <= WIN);
        float p = ok ? __expf(val - M_FIX) : 0.0f;
        lrow[r] += p;
        sP[w][ql * PSTR + nf * 16 + (lane & 15)] = f2bf(p);
      }
    }

    // ---- O += P V  (P A-frags from sP; V B-frags from swizzled image)
    short8 pf0 = *(const short8*)&sP[w][(lane & 15) * PSTR + (lane >> 4) * 8];
    short8 pf1 = *(const short8*)&sP[w][(lane & 15) * PSTR + 32 + (lane >> 4) * 8];
#pragma unroll
    for (int nf = 0; nf < 16; ++nf) {
      short8 vf0 = *(const short8*)&sVt[nf * 1024 + vb0];
      short8 vf1 = *(const short8*)&sVt[nf * 1024 + vb1];
      O[nf] = mfma_bf16(pf0, vf0, O[nf]);
      O[nf] = mfma_bf16(pf1, vf1, O[nf]);
    }
    __syncthreads();
  }

  // ---- final l reduction across the 16-lane column groups
#pragma unroll
  for (int r = 0; r < 4; ++r) {
#pragma unroll
    for (int off = 8; off >= 1; off >>= 1) lrow[r] += __shfl_xor(lrow[r], off);
  }

  // ---- store partials: PO[c][t][h][d] bf16 (raw O), ML[c][t][h][{m,l}] f32
#pragma unroll
  for (int nf = 0; nf < 16; ++nf) {
    int d = nf * 16 + (lane & 15);
#pragma unroll
    for (int r = 0; r < 4; ++r) {
      int trow = qb + w * 16 + (lane >> 4) * 4 + r;
      po[(((size_t)c * T_LEN + trow) * HN + h) * DH + d] = f2bf(O[nf][r]);
    }
  }
  if ((lane & 15) == 0) {
#pragma unroll
    for (int r = 0; r < 4; ++r) {
      int trow = qb + w * 16 + (lane >> 4) * 4 + r;
      size_t mi = (((size_t)c * T_LEN + trow) * HN + h) * 2;
      ml[mi] = M_FIX;
      ml[mi + 1] = lrow[r];
    }
  }
}

// ---------------- combine 2 partial chunks -> attnb (aliases PO chunk0) ----
// Fixed-max partials: O = (O0 + O1) / (l0 + l1).
__global__ __launch_bounds__(256) void combine_kernel(const u16* __restrict__ po,
                                                      const float* __restrict__ ml,
                                                      u16* __restrict__ attnb) {
  const int t = blockIdx.x;
  const int h = threadIdx.x >> 4;
  const int d0 = (threadIdx.x & 15) * 16;
  const size_t row = (size_t)t * HN + h;
  const float l0 = ml[row * 2 + 1];
  const float l1 = ml[(size_t)T_LEN * HN * 2 + row * 2 + 1];
  const float inv = 1.0f / (l0 + l1);
  const size_t i0 = row * DH + d0;
  const size_t i1 = (size_t)T_LEN * HN * DH + i0;
#pragma unroll
  for (int half = 0; half < 2; ++half) {
    short8 x0 = *(const short8*)(po + i0 + half * 8);
    short8 x1 = *(const short8*)(po + i1 + half * 8);
    short8 o;
#pragma unroll
    for (int j = 0; j < 8; ++j)
      o[j] = (short)f2bf((bf2f((u16)x0[j]) + bf2f((u16)x1[j])) * inv);
    *(short8*)(attnb + i0 + half * 8) = o;
  }
}

// ---------------- host launcher ----------------
extern "C" void kernel_launch(void* const* d_in, const int* in_sizes, int n_in,
                              void* d_out, int out_size, void* d_ws, size_t ws_size,
                              hipStream_t stream) {
  const float* hidden = (const float*)d_in[1];
  const float* w_qkv = (const float*)d_in[2];
  const float* w_o = (const float*)d_in[3];
  float* out = (float*)d_out;
  char* ws = (char*)d_ws;

  // Layout (peak 131,072,000 B):
  //  [0, 58,720,256):           wqkvb -> after GEMM1: PO[2] (50.3M) + ML (0.8M)
  //  [58,720,256, 80,740,352):  hb    -> after GEMM1: Vt (12.6M)
  //  [80,740,352, 131,072,000): qkvb  -> after attn:  wob (29.4M)
  u16* wqkvb = (u16*)(ws);
  u16* po = (u16*)(ws);                        // [2][T][H][256] bf16
  float* ml = (float*)(ws + 50331648);         // [2][T][H][2] f32
  u16* attnb = (u16*)(ws);                     // aliases PO0
  u16* hb = (u16*)(ws + 58720256);
  u16* vtb = (u16*)(ws + 58720256);            // aliases hb (dead after GEMM1)
  u16* qkvb = (u16*)(ws + 80740352);
  u16* wob = (u16*)(ws + 80740352);

  {
    int n = T_LEN * HID;
    cvt_kernel<<<dim3((n / 4 + 255) / 256), 256, 0, stream>>>(hidden, hb, n);
  }
  {
    int n = QKV_N * HID;
    cvt_kernel<<<dim3((n / 4 + 255) / 256), 256, 0, stream>>>(w_qkv, wqkvb, n);
  }
  // GEMM1: M=3072 N=8192 K=3584 -> 12x32 = 384 blocks (384%8==0, cpx=48)
  gemm8<1><<<dim3(384), 512, 0, stream>>>(hb, wqkvb, qkvb, QKV_N, HID, 32, 48);
  {
    int n = T_LEN * 24 * 128;
    rope_kernel<<<dim3(n / 256), 256, 0, stream>>>(qkvb);
  }
  vtrans_kernel<<<dim3(NJT, KVH), 256, 0, stream>>>(qkvb, vtb);
  attn_kernel<<<dim3(1536), 256, 0, stream>>>(qkvb, vtb, po, ml);
  {
    int n = HID * O_N;  // w_o conversion AFTER attn (overwrites qkvb region)
    cvt_kernel<<<dim3((n / 4 + 255) / 256), 256, 0, stream>>>(w_o, wob, n);
  }
  combine_kernel<<<dim3(T_LEN), 256, 0, stream>>>(po, ml, attnb);
  // GEMM2: M=3072 N=3584 K=4096 -> 12x14 = 168 blocks (168%8==0, cpx=21)
  gemm8<0><<<dim3(168), 512, 0, stream>>>(attnb, wob, out, HID, O_N, 14, 21);
}